// Round 1
// baseline (1575.300 us; speedup 1.0000x reference)
//
#include <hip/hip_runtime.h>

// PointNet SA module: gather + gated MLP (64->64->128->256) + max-pool over S.
// fp32 baseline: thread-per-point, full chain in registers, weights via
// wave-uniform scalar loads. Compute-bound on the fp32 vector pipe.

namespace {
constexpr int kB = 4, kN = 16384, kC = 103, kP = 2048, kS = 32;
constexpr int CIN = 106, C0 = 64, C1 = 64, C2 = 128, C3 = 256;

__global__ void copy_newxyz(const float* __restrict__ src, float* __restrict__ dst, int n) {
    int i = blockIdx.x * blockDim.x + threadIdx.x;
    if (i < n) dst[i] = src[i];
}

__global__ __launch_bounds__(256, 2) void pointnet_sa(
    const float* __restrict__ xyz, const float* __restrict__ features,
    const float* __restrict__ new_xyz, const int* __restrict__ idx,
    const float* __restrict__ Wg, const float* __restrict__ bg,
    const float* __restrict__ W1, const float* __restrict__ b1,
    const float* __restrict__ W2, const float* __restrict__ b2,
    const float* __restrict__ W3, const float* __restrict__ b3,
    float* __restrict__ out_pooled)  // (B, 256, P)
{
    const int t = blockIdx.x * blockDim.x + threadIdx.x;  // enumerates (b,p,s) row-major
    const int s = t & (kS - 1);
    const int p = (t >> 5) & (kP - 1);
    const int b = t >> 16;  // P*S = 65536

    const int n = idx[t];  // coalesced: idx is (B,P,S) row-major == t order

    // ---- gather: nf = [xyz[n]-new_xyz[p] (3), features[:,n] (103)] ----
    float nf[CIN];
    {
        const float* xp = xyz + ((size_t)b * kN + n) * 3;
        const float* np = new_xyz + ((size_t)b * kP + p) * 3;
        nf[0] = xp[0] - np[0];
        nf[1] = xp[1] - np[1];
        nf[2] = xp[2] - np[2];
    }
    {
        const float* fp = features + (size_t)b * kC * kN + n;
        #pragma unroll
        for (int c = 0; c < kC; ++c) nf[3 + c] = fp[(size_t)c * kN];
    }

    // ---- stage 0: gating  x0 = nf[:64] * (1 + Wg·nf + bg) ----
    float x0[C0];
    #pragma unroll
    for (int o = 0; o < C0; ++o) {
        float w = bg[o];
        #pragma unroll
        for (int c = 0; c < CIN; ++c) w = fmaf(Wg[o * CIN + c], nf[c], w);
        x0[o] = nf[o] * (1.0f + w);
    }

    // ---- stage 1: x1 = relu(W1·x0 + b1) ----
    float x1[C1];
    #pragma unroll
    for (int o = 0; o < C1; ++o) {
        float a = b1[o];
        #pragma unroll
        for (int c = 0; c < C0; ++c) a = fmaf(W1[o * C0 + c], x0[c], a);
        x1[o] = fmaxf(a, 0.0f);
    }

    // ---- stage 2: x2 = relu(W2·x1 + b2) ----
    float x2[C2];
    #pragma unroll
    for (int o = 0; o < C2; ++o) {
        float a = b2[o];
        #pragma unroll
        for (int c = 0; c < C1; ++c) a = fmaf(W2[o * C1 + c], x1[c], a);
        x2[o] = fmaxf(a, 0.0f);
    }

    // ---- stage 3 + max-pool over s (32 lanes = one s-group; wave holds 2 groups) ----
    // Rolled over o: weight row index is uniform-dynamic (s_load), acc is scalar.
    float* outp = out_pooled + ((size_t)b * C3) * kP + p;
    #pragma unroll 2
    for (int o = 0; o < C3; ++o) {
        float a = b3[o];
        #pragma unroll
        for (int c = 0; c < C2; ++c) a = fmaf(W3[o * C2 + c], x2[c], a);
        a = fmaxf(a, 0.0f);
        // butterfly max over the 32-lane s-group (xor masks < 32 stay in-half)
        #pragma unroll
        for (int m = 16; m >= 1; m >>= 1) a = fmaxf(a, __shfl_xor(a, m, 64));
        if (s == 0) outp[(size_t)o * kP] = a;
    }
}
}  // namespace

extern "C" void kernel_launch(void* const* d_in, const int* in_sizes, int n_in,
                              void* d_out, int out_size, void* d_ws, size_t ws_size,
                              hipStream_t stream) {
    const float* xyz      = (const float*)d_in[0];
    const float* features = (const float*)d_in[1];
    const float* new_xyz  = (const float*)d_in[2];
    const int*   idx      = (const int*)d_in[3];
    const float* Wg = (const float*)d_in[4];
    const float* bg = (const float*)d_in[5];
    const float* W1 = (const float*)d_in[6];
    const float* b1 = (const float*)d_in[7];
    const float* W2 = (const float*)d_in[8];
    const float* b2 = (const float*)d_in[9];
    const float* W3 = (const float*)d_in[10];
    const float* b3 = (const float*)d_in[11];
    float* out = (float*)d_out;

    // output tuple: new_xyz (B*P*3) then pooled (B*256*P)
    const int nxyz = kB * kP * 3;  // 24576
    copy_newxyz<<<(nxyz + 255) / 256, 256, 0, stream>>>(new_xyz, out, nxyz);

    float* pooled = out + nxyz;
    pointnet_sa<<<(kB * kP * kS) / 256, 256, 0, stream>>>(
        xyz, features, new_xyz, idx, Wg, bg, W1, b1, W2, b2, W3, b3, pooled);
}

// Round 2
// 1544.466 us; speedup vs baseline: 1.0200x; 1.0200x over previous
//
#include <hip/hip_runtime.h>

// PointNet SA: gather + gated MLP (106->64->64->128->256) + max-pool over S=32.
// Block-GEMM structure: 64 points/block, activations in LDS [ch][pt],
// 8 waves x 8-row register blocking, weights pre-transposed to [c][o] in d_ws
// so inner loop = 1 ds_read + 8 v_fmac with contiguous scalar (SGPR) weights.

namespace {
constexpr int kB = 4, kN = 16384, kC = 103, kP = 2048, kS = 32;
constexpr int C3 = 256;

// d_ws layout (floats): WgT[106*64] | W1T[64*64] | W2T[64*128] | W3T[128*256]
constexpr int OFF_G = 0;
constexpr int SZ_G  = 106 * 64;
constexpr int OFF_1 = OFF_G + SZ_G;          // 6784
constexpr int SZ_1  = 64 * 64;
constexpr int OFF_2 = OFF_1 + SZ_1;          // 10880
constexpr int SZ_2  = 64 * 128;
constexpr int OFF_3 = OFF_2 + SZ_2;          // 19072
constexpr int SZ_3  = 128 * 256;
constexpr int SZ_ALL = OFF_3 + SZ_3;         // 51840 floats = 207 KB

__global__ void copy_newxyz(const float* __restrict__ src, float* __restrict__ dst, int n) {
    int i = blockIdx.x * blockDim.x + threadIdx.x;
    if (i < n) dst[i] = src[i];
}

__global__ void prep_weights(const float* __restrict__ Wg, const float* __restrict__ W1,
                             const float* __restrict__ W2, const float* __restrict__ W3,
                             float* __restrict__ ws) {
    int i = blockIdx.x * blockDim.x + threadIdx.x;
    if (i >= SZ_ALL) return;
    if (i < OFF_1) {                       // WgT[c][o] <- Wg[o][c], Wg is (64,106)
        int j = i - OFF_G, c = j >> 6, o = j & 63;
        ws[i] = Wg[o * 106 + c];
    } else if (i < OFF_2) {                // W1T[c][o] <- W1[o][c], W1 is (64,64)
        int j = i - OFF_1, c = j >> 6, o = j & 63;
        ws[i] = W1[o * 64 + c];
    } else if (i < OFF_3) {                // W2T[c][o] <- W2[o][c], W2 is (128,64)
        int j = i - OFF_2, c = j >> 7, o = j & 127;
        ws[i] = W2[o * 64 + c];
    } else {                               // W3T[c][o] <- W3[o][c], W3 is (256,128)
        int j = i - OFF_3, c = j >> 8, o = j & 255;
        ws[i] = W3[o * 128 + c];
    }
}

// MODE 0: gated (x = base*(1+w)) -> LDS ; MODE 1: relu -> LDS ; MODE 2: relu -> pool -> global
template <int K, int O, int MODE>
__device__ __forceinline__ void stage(const float* __restrict__ WT, const float* __restrict__ bias,
                                      const float* in_lds, float* out_lds,
                                      const float* baseA, float* __restrict__ out_global,
                                      int lane, int wave, int p, int s) {
    constexpr int PASSES = O / 64;
    #pragma unroll
    for (int pass = 0; pass < PASSES; ++pass) {
        const int o0 = pass * 64 + wave * 8;
        float acc[8];
        #pragma unroll
        for (int r = 0; r < 8; ++r) acc[r] = bias[o0 + r];
        #pragma unroll 4
        for (int c = 0; c < K; ++c) {
            float v = in_lds[c * 64 + lane];
            const float* wrow = WT + c * O + o0;   // 8 contiguous, wave-uniform -> s_load
            #pragma unroll
            for (int r = 0; r < 8; ++r) acc[r] = fmaf(wrow[r], v, acc[r]);
        }
        if (MODE == 0) {
            #pragma unroll
            for (int r = 0; r < 8; ++r) {
                float base = baseA[(o0 + r) * 64 + lane];
                out_lds[(o0 + r) * 64 + lane] = fmaf(base, acc[r], base);  // base*(1+w)
            }
        } else if (MODE == 1) {
            #pragma unroll
            for (int r = 0; r < 8; ++r) out_lds[(o0 + r) * 64 + lane] = fmaxf(acc[r], 0.0f);
        } else {
            #pragma unroll
            for (int r = 0; r < 8; ++r) {
                float a = fmaxf(acc[r], 0.0f);
                #pragma unroll
                for (int m = 16; m >= 1; m >>= 1) a = fmaxf(a, __shfl_xor(a, m, 64));
                if (s == 0) out_global[(size_t)(o0 + r) * kP + p] = a;
            }
        }
    }
}

__global__ __launch_bounds__(512, 4) void pointnet_sa(
    const float* __restrict__ xyz, const float* __restrict__ features,
    const float* __restrict__ new_xyz, const int* __restrict__ idx,
    const float* __restrict__ ws,
    const float* __restrict__ bg, const float* __restrict__ b1,
    const float* __restrict__ b2, const float* __restrict__ b3,
    float* __restrict__ out_pooled)  // (B, 256, P)
{
    __shared__ float bufA[128 * 64];
    __shared__ float bufB[128 * 64];

    const int lane = threadIdx.x & 63;
    const int wave = threadIdx.x >> 6;
    const int pt0  = blockIdx.x * 64;          // 64 points per block, same b
    const int b    = pt0 >> 16;                // P*S = 65536 points per batch
    const int pt   = pt0 + lane;
    const int p    = (pt >> 5) & (kP - 1);
    const int s    = pt & (kS - 1);
    const int n    = idx[pt];

    // ---- gather nf[106][64] into bufA ----
    if (wave == 0) {
        const float* xp = xyz + ((size_t)b * kN + n) * 3;
        const float* np = new_xyz + ((size_t)b * kP + p) * 3;
        bufA[0 * 64 + lane] = xp[0] - np[0];
        bufA[1 * 64 + lane] = xp[1] - np[1];
        bufA[2 * 64 + lane] = xp[2] - np[2];
    }
    const float* fb = features + (size_t)b * kC * kN + n;
    for (int c = wave; c < kC; c += 8)
        bufA[(3 + c) * 64 + lane] = fb[(size_t)c * kN];
    __syncthreads();

    const float* WgT = ws + OFF_G;
    const float* W1T = ws + OFF_1;
    const float* W2T = ws + OFF_2;
    const float* W3T = ws + OFF_3;
    float* outg = out_pooled + (size_t)b * C3 * kP;

    stage<106,  64, 0>(WgT, bg, bufA, bufB, bufA, nullptr, lane, wave, p, s);
    __syncthreads();
    stage< 64,  64, 1>(W1T, b1, bufB, bufA, nullptr, nullptr, lane, wave, p, s);
    __syncthreads();
    stage< 64, 128, 1>(W2T, b2, bufA, bufB, nullptr, nullptr, lane, wave, p, s);
    __syncthreads();
    stage<128, 256, 2>(W3T, b3, bufB, nullptr, nullptr, outg, lane, wave, p, s);
}
}  // namespace

extern "C" void kernel_launch(void* const* d_in, const int* in_sizes, int n_in,
                              void* d_out, int out_size, void* d_ws, size_t ws_size,
                              hipStream_t stream) {
    const float* xyz      = (const float*)d_in[0];
    const float* features = (const float*)d_in[1];
    const float* new_xyz  = (const float*)d_in[2];
    const int*   idx      = (const int*)d_in[3];
    const float* Wg = (const float*)d_in[4];
    const float* bg = (const float*)d_in[5];
    const float* W1 = (const float*)d_in[6];
    const float* b1 = (const float*)d_in[7];
    const float* W2 = (const float*)d_in[8];
    const float* b2 = (const float*)d_in[9];
    const float* W3 = (const float*)d_in[10];
    const float* b3 = (const float*)d_in[11];
    float* out = (float*)d_out;
    float* ws  = (float*)d_ws;

    // output tuple: new_xyz (B*P*3) then pooled (B*256*P)
    const int nxyz = kB * kP * 3;
    copy_newxyz<<<(nxyz + 255) / 256, 256, 0, stream>>>(new_xyz, out, nxyz);

    prep_weights<<<(SZ_ALL + 255) / 256, 256, 0, stream>>>(Wg, W1, W2, W3, ws);

    float* pooled = out + nxyz;
    pointnet_sa<<<(kB * kP * kS) / 64, 512, 0, stream>>>(
        xyz, features, new_xyz, idx, ws, bg, b1, b2, b3, pooled);
}

// Round 4
// 597.396 us; speedup vs baseline: 2.6369x; 2.5853x over previous
//
#include <hip/hip_runtime.h>

// PointNet SA: gather + gated MLP (106->64->64->128->256) + max-pool over S=32.
// v3: weights via FORCED-SCALAR addresses (readfirstlane -> s_load on SMEM pipe),
// activations in LDS [point][channel] so each lane does ds_read_b128 (4 ch/instr).
// 8 waves x 8 output channels, 64 points/block.

namespace {
constexpr int kB = 4, kN = 16384, kC = 103, kP = 2048, kS = 32;
constexpr int C3 = 256;

// d_ws layout (floats): WgT[108*64] (zero-padded rows 106,107) | W1T[64*64] | W2T[64*128] | W3T[128*256]
constexpr int OFF_G = 0;
constexpr int SZ_G  = 108 * 64;              // 6912
constexpr int OFF_1 = OFF_G + SZ_G;
constexpr int SZ_1  = 64 * 64;
constexpr int OFF_2 = OFF_1 + SZ_1;          // 11008
constexpr int SZ_2  = 64 * 128;
constexpr int OFF_3 = OFF_2 + SZ_2;          // 19200
constexpr int SZ_3  = 128 * 256;
constexpr int SZ_ALL = OFF_3 + SZ_3;         // 51968 floats = 208 KB

// LDS strides (dwords); all chosen 16B-aligned and bank-conflict-free for b128.
constexpr int LD_IN = 108;   // input nf: 106 ch + 2 zero pad
constexpr int LD_64 = 68;    // 64-ch activations
constexpr int LD_128 = 132;  // 128-ch activations

__global__ void copy_newxyz(const float* __restrict__ src, float* __restrict__ dst, int n) {
    int i = blockIdx.x * blockDim.x + threadIdx.x;
    if (i < n) dst[i] = src[i];
}

__global__ void prep_weights(const float* __restrict__ Wg, const float* __restrict__ W1,
                             const float* __restrict__ W2, const float* __restrict__ W3,
                             float* __restrict__ ws) {
    int i = blockIdx.x * blockDim.x + threadIdx.x;
    if (i >= SZ_ALL) return;
    if (i < OFF_1) {                       // WgT[c][o] <- Wg[o][c], Wg is (64,106); rows 106,107 = 0
        int j = i, c = j >> 6, o = j & 63;
        ws[i] = (c < 106) ? Wg[o * 106 + c] : 0.0f;
    } else if (i < OFF_2) {                // W1T[c][o] <- W1[o][c], W1 is (64,64)
        int j = i - OFF_1, c = j >> 6, o = j & 63;
        ws[i] = W1[o * 64 + c];
    } else if (i < OFF_3) {                // W2T[c][o] <- W2[o][c], W2 is (128,64)
        int j = i - OFF_2, c = j >> 7, o = j & 127;
        ws[i] = W2[o * 64 + c];
    } else {                               // W3T[c][o] <- W3[o][c], W3 is (256,128)
        int j = i - OFF_3, c = j >> 8, o = j & 255;
        ws[i] = W3[o * 128 + c];
    }
}

// MODE 0: gated (x = base*(1+w)) -> LDS ; MODE 1: relu -> LDS ; MODE 2: relu -> pool -> global
template <int K4, int LDIN, int O, int LDOUT, int MODE>
__device__ __forceinline__ void stage(const float* __restrict__ WT, const float* __restrict__ bias,
                                      const float* in_lds, float* out_lds,
                                      float* __restrict__ out_global,
                                      int lane, int wave, int p, int s) {
    constexpr int PASSES = O / 64;
    const float* inp = in_lds + lane * LDIN;
    #pragma unroll
    for (int pass = 0; pass < PASSES; ++pass) {
        // FORCE scalar: weight/bias addresses become SGPR -> s_load (SMEM pipe).
        const int o0 = __builtin_amdgcn_readfirstlane(pass * 64 + wave * 8);
        float acc[8];
        #pragma unroll
        for (int r = 0; r < 8; ++r) acc[r] = bias[o0 + r];
        #pragma unroll 4
        for (int c4 = 0; c4 < K4; ++c4) {
            float4 v = *(const float4*)(inp + c4 * 4);          // ds_read_b128: 4 channels
            const float* wb = WT + (c4 * 4) * O + o0;           // fully scalar address
            #pragma unroll
            for (int cc = 0; cc < 4; ++cc) {
                const float x = (&v.x)[cc];
                #pragma unroll
                for (int r = 0; r < 8; ++r)
                    acc[r] = fmaf(wb[cc * O + r], x, acc[r]);   // weight from SGPR
            }
        }
        if (MODE == 0) {
            // base = input channels [o0 .. o0+7] of this lane's point
            float4 b0 = *(const float4*)(inp + o0);
            float4 b1 = *(const float4*)(inp + o0 + 4);
            float4 w0, w1;
            #pragma unroll
            for (int r = 0; r < 4; ++r) (&w0.x)[r] = fmaf((&b0.x)[r], acc[r],     (&b0.x)[r]);
            #pragma unroll
            for (int r = 0; r < 4; ++r) (&w1.x)[r] = fmaf((&b1.x)[r], acc[4 + r], (&b1.x)[r]);
            *(float4*)(out_lds + lane * LDOUT + o0)     = w0;
            *(float4*)(out_lds + lane * LDOUT + o0 + 4) = w1;
        } else if (MODE == 1) {
            float4 w0, w1;
            #pragma unroll
            for (int r = 0; r < 4; ++r) (&w0.x)[r] = fmaxf(acc[r],     0.0f);
            #pragma unroll
            for (int r = 0; r < 4; ++r) (&w1.x)[r] = fmaxf(acc[4 + r], 0.0f);
            *(float4*)(out_lds + lane * LDOUT + o0)     = w0;
            *(float4*)(out_lds + lane * LDOUT + o0 + 4) = w1;
        } else {
            #pragma unroll
            for (int r = 0; r < 8; ++r) {
                float a = fmaxf(acc[r], 0.0f);
                #pragma unroll
                for (int m = 16; m >= 1; m >>= 1) a = fmaxf(a, __shfl_xor(a, m, 64));
                if (s == 0) out_global[(size_t)(o0 + r) * kP + p] = a;
            }
        }
    }
}

__global__ __launch_bounds__(512, 4) void pointnet_sa(
    const float* __restrict__ xyz, const float* __restrict__ features,
    const float* __restrict__ new_xyz, const int* __restrict__ idx,
    const float* __restrict__ ws,
    const float* __restrict__ bg, const float* __restrict__ b1,
    const float* __restrict__ b2, const float* __restrict__ b3,
    float* __restrict__ out_pooled)  // (B, 256, P)
{
    __shared__ float bufBig[64 * LD_128];  // input nf (stride 108) THEN stage-2 out (stride 132)
    __shared__ float buf0[64 * LD_64];
    __shared__ float buf1[64 * LD_64];

    const int lane = threadIdx.x & 63;
    const int wave = threadIdx.x >> 6;
    const int pt0  = blockIdx.x * 64;          // 64 points per block, same b
    const int b    = pt0 >> 16;                // P*S = 65536 points per batch
    const int pt   = pt0 + lane;
    const int p    = (pt >> 5) & (kP - 1);
    const int s    = pt & (kS - 1);
    const int n    = idx[pt];

    // ---- gather nf into bufBig[pt][ch] (stride 108) ----
    if (wave == 0) {
        const float* xp = xyz + ((size_t)b * kN + n) * 3;
        const float* np = new_xyz + ((size_t)b * kP + p) * 3;
        bufBig[lane * LD_IN + 0] = xp[0] - np[0];
        bufBig[lane * LD_IN + 1] = xp[1] - np[1];
        bufBig[lane * LD_IN + 2] = xp[2] - np[2];
    }
    if (wave == 1) {
        bufBig[lane * LD_IN + 106] = 0.0f;     // zero pad channels
        bufBig[lane * LD_IN + 107] = 0.0f;
    }
    const float* fb = features + (size_t)b * kC * kN + n;
    for (int c = wave; c < kC; c += 8)
        bufBig[lane * LD_IN + 3 + c] = fb[(size_t)c * kN];
    __syncthreads();

    const float* WgT = ws + OFF_G;
    const float* W1T = ws + OFF_1;
    const float* W2T = ws + OFF_2;
    const float* W3T = ws + OFF_3;
    float* outg = out_pooled + (size_t)b * C3 * kP;

    stage<27, LD_IN,  64,  LD_64,  0>(WgT, bg, bufBig, buf0, nullptr, lane, wave, p, s);
    __syncthreads();
    stage<16, LD_64,  64,  LD_64,  1>(W1T, b1, buf0, buf1, nullptr, lane, wave, p, s);
    __syncthreads();
    stage<16, LD_64,  128, LD_128, 1>(W2T, b2, buf1, bufBig, nullptr, lane, wave, p, s);
    __syncthreads();
    stage<32, LD_128, 256, 0,      2>(W3T, b3, bufBig, nullptr, outg, lane, wave, p, s);
}
}  // namespace

extern "C" void kernel_launch(void* const* d_in, const int* in_sizes, int n_in,
                              void* d_out, int out_size, void* d_ws, size_t ws_size,
                              hipStream_t stream) {
    const float* xyz      = (const float*)d_in[0];
    const float* features = (const float*)d_in[1];
    const float* new_xyz  = (const float*)d_in[2];
    const int*   idx      = (const int*)d_in[3];
    const float* Wg = (const float*)d_in[4];
    const float* bg = (const float*)d_in[5];
    const float* W1 = (const float*)d_in[6];
    const float* b1 = (const float*)d_in[7];
    const float* W2 = (const float*)d_in[8];
    const float* b2 = (const float*)d_in[9];
    const float* W3 = (const float*)d_in[10];
    const float* b3 = (const float*)d_in[11];
    float* out = (float*)d_out;
    float* ws  = (float*)d_ws;

    // output tuple: new_xyz (B*P*3) then pooled (B*256*P)
    const int nxyz = kB * kP * 3;
    copy_newxyz<<<(nxyz + 255) / 256, 256, 0, stream>>>(new_xyz, out, nxyz);

    prep_weights<<<(SZ_ALL + 255) / 256, 256, 0, stream>>>(Wg, W1, W2, W3, ws);

    float* pooled = out + nxyz;
    pointnet_sa<<<(kB * kP * kS) / 64, 512, 0, stream>>>(
        xyz, features, new_xyz, idx, ws, bg, b1, b2, b3, pooled);
}

// Round 6
// 278.235 us; speedup vs baseline: 5.6618x; 2.1471x over previous
//
#include <hip/hip_runtime.h>

// PointNet SA via MFMA: gather -> gated MLP (106->64->64->128->256) -> max-pool(S=32).
// fp32 emulated as bf16 hi/lo split: D = Ah*Bh + Ah*Bl + Al*Bh (3 mfma, ~2^-17 rel err).
// Activations: LDS bf16 planes [p][c], XOR-swizzled. Weights: hi/lo planes in d_ws,
// A-fragments loaded straight from global (L2-resident). 64 pts/block, 8 waves.

namespace {
constexpr int kB = 4, kN = 16384, kC = 103, kP = 2048, kS = 32;

using short8 = __attribute__((ext_vector_type(8))) short;
using short4 = __attribute__((ext_vector_type(4))) short;
using f32x4  = __attribute__((ext_vector_type(4))) float;

// d_ws (shorts): per-stage weight planes, zero-padded K, row-major [O][Kpad]
constexpr int WG_HI = 0,      WG_LO = 8192;    // 64 x 128
constexpr int W1_HI = 16384,  W1_LO = 20480;   // 64 x 64
constexpr int W2_HI = 24576,  W2_LO = 32768;   // 128 x 64
constexpr int W3_HI = 40960,  W3_LO = 73728;   // 256 x 128
constexpr int WS_SHORTS = 106496;              // 208 KB

__device__ __forceinline__ unsigned short f2bf(float x) {
    unsigned u = __float_as_uint(x);
    u += 0x7fffu + ((u >> 16) & 1u);           // round-to-nearest-even
    return (unsigned short)(u >> 16);
}
__device__ __forceinline__ float bf2f(unsigned short h) {
    return __uint_as_float((unsigned)h << 16);
}

__global__ void copy_newxyz(const float* __restrict__ src, float* __restrict__ dst, int n) {
    int i = blockIdx.x * blockDim.x + threadIdx.x;
    if (i < n) dst[i] = src[i];
}

__global__ void prep_weights(const float* __restrict__ Wg, const float* __restrict__ W1,
                             const float* __restrict__ W2, const float* __restrict__ W3,
                             short* __restrict__ ws) {
    int i = blockIdx.x * blockDim.x + threadIdx.x;
    if (i >= 53248) return;                    // padded elems per plane-pair
    float w; int hi, lo, j;
    if (i < 8192)       { j = i;         int o = j >> 7, c = j & 127; w = (c < 106) ? Wg[o * 106 + c] : 0.f; hi = WG_HI; lo = WG_LO; }
    else if (i < 12288) { j = i - 8192;  int o = j >> 6, c = j & 63;  w = W1[o * 64 + c];  hi = W1_HI; lo = W1_LO; }
    else if (i < 20480) { j = i - 12288; int o = j >> 6, c = j & 63;  w = W2[o * 64 + c];  hi = W2_HI; lo = W2_LO; }
    else                { j = i - 20480; int o = j >> 7, c = j & 127; w = W3[o * 128 + c]; hi = W3_HI; lo = W3_LO; }
    unsigned short h = f2bf(w);
    ws[hi + j] = (short)h;
    ws[lo + j] = (short)f2bf(w - bf2f(h));
}

// A: m=lane&15 (row of W), k=8*(lane>>4)+j  -> W row-major [O][KT*32] direct 16B load
// B: n=lane&15 (point),    k=8*(lane>>4)+j  -> LDS plane [p][c], swizzled
// D: n=lane&15, m=4*(lane>>4)+reg  (verified layout, learn_hip m89)
template<int NOT, int NPT, int KT, int LDC>
__device__ __forceinline__ void gemm_stage(
    const short* __restrict__ xh, const short* __restrict__ xl,
    const short* __restrict__ wh, const short* __restrict__ wl,
    const float* __restrict__ bias,
    int ot0, int pt0t, int lane, f32x4 (&acc)[NOT][NPT])
{
    const int q = lane >> 4, n16 = lane & 15;
    #pragma unroll
    for (int i = 0; i < NOT; ++i) {
        const f32x4 binit = *(const f32x4*)(bias + (ot0 + i) * 16 + 4 * q);
        #pragma unroll
        for (int j = 0; j < NPT; ++j) acc[i][j] = binit;
    }
    #pragma unroll
    for (int kt = 0; kt < KT; ++kt) {
        const int k0 = kt * 32 + q * 8;
        short8 bh[NPT], bl[NPT];
        #pragma unroll
        for (int j = 0; j < NPT; ++j) {
            const int p = (pt0t + j) * 16 + n16;
            const int e = p * LDC + (k0 ^ ((p & 7) << 3));
            bh[j] = *(const short8*)(xh + e);
            bl[j] = *(const short8*)(xl + e);
        }
        #pragma unroll
        for (int i = 0; i < NOT; ++i) {
            const size_t we = (size_t)((ot0 + i) * 16 + n16) * (KT * 32) + k0;
            const short8 ah = *(const short8*)(wh + we);
            const short8 al = *(const short8*)(wl + we);
            #pragma unroll
            for (int j = 0; j < NPT; ++j) {
                acc[i][j] = __builtin_amdgcn_mfma_f32_16x16x32_bf16(ah, bh[j], acc[i][j], 0, 0, 0);
                acc[i][j] = __builtin_amdgcn_mfma_f32_16x16x32_bf16(ah, bl[j], acc[i][j], 0, 0, 0);
                acc[i][j] = __builtin_amdgcn_mfma_f32_16x16x32_bf16(al, bh[j], acc[i][j], 0, 0, 0);
            }
        }
    }
}

// GATE: v = base*(1+acc), base from nf planes; else v = relu(acc). Store hi/lo bf16.
template<int NOT, int NPT, bool GATE, int LDCO>
__device__ __forceinline__ void store_act(
    f32x4 (&acc)[NOT][NPT], short* __restrict__ oh, short* __restrict__ ol,
    const short* __restrict__ nfh, const short* __restrict__ nfl,
    int ot0, int pt0t, int lane)
{
    const int q = lane >> 4, n16 = lane & 15;
    #pragma unroll
    for (int i = 0; i < NOT; ++i) {
        const int ob = (ot0 + i) * 16 + 4 * q;
        #pragma unroll
        for (int j = 0; j < NPT; ++j) {
            const int p = (pt0t + j) * 16 + n16;
            const int cs = ob ^ ((p & 7) << 3);
            float v[4];
            #pragma unroll
            for (int r = 0; r < 4; ++r) v[r] = acc[i][j][r];
            if (GATE) {
                const short4 h4 = *(const short4*)(nfh + p * 128 + cs);
                const short4 l4 = *(const short4*)(nfl + p * 128 + cs);
                #pragma unroll
                for (int r = 0; r < 4; ++r) {
                    const float base = bf2f((unsigned short)h4[r]) + bf2f((unsigned short)l4[r]);
                    v[r] = fmaf(base, v[r], base);      // base*(1+w)
                }
            } else {
                #pragma unroll
                for (int r = 0; r < 4; ++r) v[r] = fmaxf(v[r], 0.f);
            }
            short4 h4o, l4o;
            #pragma unroll
            for (int r = 0; r < 4; ++r) {
                const unsigned short h = f2bf(v[r]);
                h4o[r] = (short)h;
                l4o[r] = (short)f2bf(v[r] - bf2f(h));
            }
            *(short4*)(oh + p * LDCO + cs) = h4o;
            *(short4*)(ol + p * LDCO + cs) = l4o;
        }
    }
}

__global__ __launch_bounds__(512, 4) void pointnet_sa(
    const float* __restrict__ xyz, const float* __restrict__ features,
    const float* __restrict__ new_xyz, const int* __restrict__ idx,
    const short* __restrict__ ws,
    const float* __restrict__ bg, const float* __restrict__ b1,
    const float* __restrict__ b2, const float* __restrict__ b3,
    float* __restrict__ out_pooled)  // (B, 256, P)
{
    __shared__ short smem[32768];                  // 64 KB
    short* NFh = smem;          short* NFl = smem + 8192;    // [64][128] each
    short* X0h = smem + 16384;  short* X0l = smem + 20480;   // [64][64]
    short* X1h = smem + 24576;  short* X1l = smem + 28672;   // [64][64]
    short* X2h = NFh;           short* X2l = NFl;            // alias (NF dead after stage g)

    const int tid = threadIdx.x, lane = tid & 63, wave = tid >> 6;
    const int q = lane >> 4, n16 = lane & 15;
    const int pt0 = blockIdx.x * 64;
    const int b = pt0 >> 16;                       // P*S = 65536 points per batch

    // ---- gather: nf[p][c] -> hi/lo planes (c in [0,128), zero-padded 106..127) ----
    {
        const int p = tid & 63;
        const int cg = tid >> 6;
        const int pt = pt0 + p;
        const int n = idx[pt];
        const int pp = (pt >> 5) & (kP - 1);
        const float* fb = features + (size_t)b * kC * kN + n;
        const float* xp = xyz + ((size_t)b * kN + n) * 3;
        const float* np = new_xyz + ((size_t)b * kP + pp) * 3;
        for (int c = cg; c < 128; c += 8) {
            float v;
            if (c < 3)        v = xp[c] - np[c];
            else if (c < 106) v = fb[(size_t)(c - 3) * kN];
            else              v = 0.f;
            const unsigned short h = f2bf(v);
            const int cs = c ^ ((p & 7) << 3);
            NFh[p * 128 + cs] = (short)h;
            NFl[p * 128 + cs] = (short)f2bf(v - bf2f(h));
        }
    }
    __syncthreads();

    // ---- stage g: w = Wg*nf + bg ; x0 = nf[:64]*(1+w) ----
    {
        f32x4 acc[1][2];
        gemm_stage<1, 2, 4, 128>(NFh, NFl, ws + WG_HI, ws + WG_LO, bg,
                                 wave & 3, 2 * (wave >> 2), lane, acc);
        store_act<1, 2, true, 64>(acc, X0h, X0l, NFh, NFl, wave & 3, 2 * (wave >> 2), lane);
    }
    __syncthreads();

    // ---- stage 1: x1 = relu(W1*x0 + b1) ----
    {
        f32x4 acc[1][2];
        gemm_stage<1, 2, 2, 64>(X0h, X0l, ws + W1_HI, ws + W1_LO, b1,
                                wave & 3, 2 * (wave >> 2), lane, acc);
        store_act<1, 2, false, 64>(acc, X1h, X1l, nullptr, nullptr, wave & 3, 2 * (wave >> 2), lane);
    }
    __syncthreads();

    // ---- stage 2: x2 = relu(W2*x1 + b2) ----
    {
        f32x4 acc[2][2];
        gemm_stage<2, 2, 2, 64>(X1h, X1l, ws + W2_HI, ws + W2_LO, b2,
                                2 * (wave & 3), 2 * (wave >> 2), lane, acc);
        store_act<2, 2, false, 128>(acc, X2h, X2l, nullptr, nullptr, 2 * (wave & 3), 2 * (wave >> 2), lane);
    }
    __syncthreads();

    // ---- stage 3: relu(W3*x2 + b3) -> max over s (32 pts = 2 p-tiles) ----
    {
        f32x4 acc[2][4];
        gemm_stage<2, 4, 4, 128>(X2h, X2l, ws + W3_HI, ws + W3_LO, b3,
                                 2 * wave, 0, lane, acc);
        #pragma unroll
        for (int i = 0; i < 2; ++i) {
            #pragma unroll
            for (int sg = 0; sg < 2; ++sg) {
                #pragma unroll
                for (int r = 0; r < 4; ++r) {
                    float a = fmaxf(acc[i][2 * sg][r], acc[i][2 * sg + 1][r]);
                    a = fmaxf(a, __shfl_xor(a, 1, 16));
                    a = fmaxf(a, __shfl_xor(a, 2, 16));
                    a = fmaxf(a, __shfl_xor(a, 4, 16));
                    a = fmaxf(a, __shfl_xor(a, 8, 16));
                    a = fmaxf(a, 0.f);
                    if (n16 == 0) {
                        const int o = (2 * wave + i) * 16 + 4 * q + r;
                        const int g = (pt0 >> 5) + sg;                 // flat (b*P + p)
                        out_pooled[((size_t)(g >> 11) * 256 + o) * kP + (g & (kP - 1))] = a;
                    }
                }
            }
        }
    }
}
}  // namespace

extern "C" void kernel_launch(void* const* d_in, const int* in_sizes, int n_in,
                              void* d_out, int out_size, void* d_ws, size_t ws_size,
                              hipStream_t stream) {
    const float* xyz      = (const float*)d_in[0];
    const float* features = (const float*)d_in[1];
    const float* new_xyz  = (const float*)d_in[2];
    const int*   idx      = (const int*)d_in[3];
    const float* Wg = (const float*)d_in[4];
    const float* bg = (const float*)d_in[5];
    const float* W1 = (const float*)d_in[6];
    const float* b1 = (const float*)d_in[7];
    const float* W2 = (const float*)d_in[8];
    const float* b2 = (const float*)d_in[9];
    const float* W3 = (const float*)d_in[10];
    const float* b3 = (const float*)d_in[11];
    float* out = (float*)d_out;
    short* ws  = (short*)d_ws;

    const int nxyz = kB * kP * 3;
    copy_newxyz<<<(nxyz + 255) / 256, 256, 0, stream>>>(new_xyz, out, nxyz);

    prep_weights<<<(53248 + 255) / 256, 256, 0, stream>>>(Wg, W1, W2, W3, ws);

    float* pooled = out + nxyz;
    pointnet_sa<<<(kB * kP * kS) / 64, 512, 0, stream>>>(
        xyz, features, new_xyz, idx, ws, bg, b1, b2, b3, pooled);
}